// Round 18
// baseline (99.039 us; speedup 1.0000x reference)
//
#include <hip/hip_runtime.h>
#include <hip/hip_bf16.h>

// Problem constants
#define Bv 4
#define Sv 4096
#define Dv 1024
#define Hv 16
#define Ov 64
#define NCv 64
#define BHv 64

typedef __attribute__((ext_vector_type(8))) short bf16x8;
typedef __attribute__((ext_vector_type(4))) unsigned short u16x4;
typedef __attribute__((ext_vector_type(8))) unsigned short u16x8;
typedef __attribute__((ext_vector_type(16))) float f32x16;
#define MFMA32(a, b, c) __builtin_amdgcn_mfma_f32_32x32x16_bf16(a, b, c, 0, 0, 0)

__device__ __forceinline__ unsigned short f2bs(float f) {
  union { __hip_bfloat16 h; unsigned short u; } v;
  v.h = __float2bfloat16(f);
  return v.u;
}
__device__ __forceinline__ float b2f(unsigned short u) {
  union { unsigned u; float f; } v; v.u = ((unsigned)u) << 16; return v.f;
}
__device__ __forceinline__ float elu1(float a) {
  return a > 0.f ? a + 1.f : __expf(a);
}
__device__ __forceinline__ f32x16 zero16() {
  f32x16 v;
#pragma unroll
  for (int i = 0; i < 16; ++i) v[i] = 0.f;
  return v;
}
__device__ __forceinline__ bf16x8 ones8() {
  union { u16x8 u; bf16x8 h; } r;
#pragma unroll
  for (int i = 0; i < 8; ++i) r.u[i] = 0x3F80;   // bf16 1.0
  return r.h;
}

// ---------------------------------------------------------------------------
// K0 prep: Wq/Wk/Wv [h][d][o] -> bf16 [h][o][d]; Wp [d][o2] -> bf16 [o2][d]
// ---------------------------------------------------------------------------
__global__ __launch_bounds__(256) void k_prep_w(
    const float* __restrict__ Wq, const float* __restrict__ Wk,
    const float* __restrict__ Wv, const float* __restrict__ Wp,
    unsigned short* __restrict__ wqT, unsigned short* __restrict__ wkT,
    unsigned short* __restrict__ wvT, unsigned short* __restrict__ wpT)
{
  const int blk = blockIdx.x, tid = threadIdx.x;
  if (blk < 16) {
    int h = blk;
    for (int j = tid; j < 4096; j += 256) {       // j = o*64 + d (output idx)
      int o = j >> 6, d = j & 63;
      int src = h * 4096 + d * 64 + o;
      wqT[h * 4096 + j] = f2bs(Wq[src]);
      wkT[h * 4096 + j] = f2bs(Wk[src]);
      wvT[h * 4096 + j] = f2bs(Wv[src]);
    }
  } else {
    int b2 = blk - 16;
#pragma unroll
    for (int k = 0; k < 4; ++k) {
      int j = b2 * 1024 + tid + k * 256;          // j = o2*1024 + d
      int o = j >> 10, d = j & 1023;
      wpT[j] = f2bs(Wp[d * 64 + o]);
    }
  }
}

// ---------------------------------------------------------------------------
// K1 (2 chunks/block, reg-held weight frags): per (bh, chunk-pair):
//   K=elu1(x Wk), V=x Wv; mir[o][e]=(K^T V)^T bf16; zmir[e]=colsum(K) bf16
// Weights staged ONCE, fragments kept in registers across both chunks.
// ---------------------------------------------------------------------------
__global__ __launch_bounds__(256) void k_chunk_state(
    const float* __restrict__ x, const unsigned short* __restrict__ wkT,
    const unsigned short* __restrict__ wvT, unsigned short* __restrict__ mir,
    unsigned short* __restrict__ zmir)
{
  __shared__ __align__(16) unsigned short Xb[64][72];   // x tile -> mir stage
  __shared__ __align__(16) unsigned short Kt[64][72];   // WkT -> K^T[e][t]
  __shared__ __align__(16) unsigned short Vt[64][72];   // WvT -> V^T[o][t]

  const int tid = threadIdx.x, blk = blockIdx.x;
  const int cp = blk & 31, bh = blk >> 5, h = bh & 15, b = bh >> 4;
  const int l = tid & 63, w = tid >> 6;
  const int wr = w >> 1, wc = w & 1;
  const int l31 = l & 31, g = l >> 5;

  // --- coalesced weight loads -> LDS (once per block) ---
  const unsigned short* wkp = wkT + h * 4096;
  const unsigned short* wvp = wvT + h * 4096;
#pragma unroll
  for (int it = 0; it < 2; ++it) {
    int j = tid * 8 + it * 2048;
    int r = j >> 6, col = j & 63;
    *(uint4*)&Kt[r][col] = *(const uint4*)&wkp[j];
    *(uint4*)&Vt[r][col] = *(const uint4*)&wvp[j];
  }
  __syncthreads();
  // weight fragments -> registers (the only LDS reads of the weight copies)
  bf16x8 wkf[4], wvf[4];
#pragma unroll
  for (int j = 0; j < 4; ++j) {
    wkf[j] = *(const bf16x8*)&Kt[wc * 32 + l31][j * 16 + g * 8];
    wvf[j] = *(const bf16x8*)&Vt[wc * 32 + l31][j * 16 + g * 8];
  }

#pragma unroll
  for (int cc = 0; cc < 2; ++cc) {
    const int c = cp * 2 + cc;
    const size_t sblk = (size_t)(bh * 64 + c);
    if (cc) __syncthreads();   // prev chunk's buffer reads complete

    // coalesced x load + cvt -> Xb
    const float* xbase = x + ((size_t)(b * Sv + c * 64)) * 1024 + h * 64;
#pragma unroll
    for (int it = 0; it < 4; ++it) {
      int u = tid + it * 256;
      int r = u >> 4, seg = u & 15;
      float4 f = *(const float4*)(xbase + (size_t)r * 1024 + seg * 4);
      u16x4 p; p[0] = f2bs(f.x); p[1] = f2bs(f.y); p[2] = f2bs(f.z); p[3] = f2bs(f.w);
      *(u16x4*)&Xb[r][seg * 4] = p;
    }
    __syncthreads();   // bar0: x staged

    bf16x8 xa[4];
#pragma unroll
    for (int j = 0; j < 4; ++j)
      xa[j] = *(const bf16x8*)&Xb[wr * 32 + l31][j * 16 + g * 8];
    // K, V ladders (register weight frags): D[t][e]
    f32x16 kacc = zero16(), vacc = zero16();
#pragma unroll
    for (int j = 0; j < 4; ++j) {
      kacc = MFMA32(xa[j], wkf[j], kacc);
      vacc = MFMA32(xa[j], wvf[j], vacc);
    }
    __syncthreads();   // bar1: x consumed

    // stage K^T[e][t] / V^T[o][t], packed along t (overwrites weight copies)
#pragma unroll
    for (int q4 = 0; q4 < 4; ++q4) {
      u16x4 pk, pv;
#pragma unroll
      for (int i = 0; i < 4; ++i) {
        pk[i] = f2bs(elu1(kacc[q4 * 4 + i]));
        pv[i] = f2bs(vacc[q4 * 4 + i]);
      }
      *(u16x4*)&Kt[wc * 32 + l31][wr * 32 + 8 * q4 + 4 * g] = pk;
      *(u16x4*)&Vt[wc * 32 + l31][wr * 32 + 8 * q4 + 4 * g] = pv;
    }
    __syncthreads();   // bar2: K^T, V^T staged

    // KtV: D[e][o]; z = ones . K (col-replicated)
    f32x16 sacc = zero16(), zacc = zero16();
    const bf16x8 one = ones8();
#pragma unroll
    for (int j = 0; j < 4; ++j) {
      bf16x8 aK = *(const bf16x8*)&Kt[wr * 32 + l31][j * 16 + g * 8];
      bf16x8 vB = *(const bf16x8*)&Vt[wc * 32 + l31][j * 16 + g * 8];
      sacc = MFMA32(aK, vB, sacc);
      bf16x8 kB = *(const bf16x8*)&Kt[wc * 32 + l31][j * 16 + g * 8];
      zacc = MFMA32(one, kB, zacc);
    }
    // stage mir[o][e] into Xb (own row; x fully consumed at bar1)
#pragma unroll
    for (int q4 = 0; q4 < 4; ++q4) {
      u16x4 p;
#pragma unroll
      for (int i = 0; i < 4; ++i) p[i] = f2bs(sacc[q4 * 4 + i]);
      *(u16x4*)&Xb[wc * 32 + l31][wr * 32 + 8 * q4 + 4 * g] = p;
    }
    __syncthreads();   // bar3: mir staged

    // coalesced mir store
    unsigned short* mp = mir + sblk * 4096;
#pragma unroll
    for (int it = 0; it < 2; ++it) {
      int j = tid * 8 + it * 2048;
      int r = j >> 6, col = j & 63;
      *(uint4*)&mp[j] = *(const uint4*)&Xb[r][col];
    }
    if (w < 2 && g == 0)
      zmir[sblk * 64 + wc * 32 + l31] = f2bs(zacc[0]);
  }
}

// ---------------------------------------------------------------------------
// K2: exclusive prefix over chunks — u32-vectorized (2 bf16/thread).
// grid = 64 bh * 9 groups (8 mir + 1 z).
// ---------------------------------------------------------------------------
__global__ __launch_bounds__(256) void k_prefix(
    unsigned short* __restrict__ mir, unsigned short* __restrict__ zmir)
{
  const int bh = blockIdx.x / 9, g = blockIdx.x % 9;
  const int tid = threadIdx.x;
  if (g < 8) {
    size_t base = (size_t)bh * 64 * 4096 + g * 512 + tid * 2;
    const unsigned short* mp = mir + base;
    unsigned v[64];
#pragma unroll
    for (int cc = 0; cc < 64; ++cc)
      v[cc] = *(const unsigned*)(mp + (size_t)cc * 4096);
    float c0 = 0.f, c1 = 0.f;
#pragma unroll
    for (int cc = 0; cc < 64; ++cc) {
      float f0 = b2f((unsigned short)(v[cc] & 0xffffu));
      float f1 = b2f((unsigned short)(v[cc] >> 16));
      v[cc] = (unsigned)f2bs(c0) | ((unsigned)f2bs(c1) << 16);
      c0 += f0; c1 += f1;
    }
    unsigned short* mw = mir + base;
#pragma unroll
    for (int cc = 0; cc < 64; ++cc)
      *(unsigned*)(mw + (size_t)cc * 4096) = v[cc];
  } else if (tid < 64) {
    size_t base = (size_t)bh * 64 * 64 + tid;
    unsigned short v[64];
#pragma unroll
    for (int cc = 0; cc < 64; ++cc) v[cc] = zmir[base + (size_t)cc * 64];
    float carry = 0.f;
#pragma unroll
    for (int cc = 0; cc < 64; ++cc) {
      float f = b2f(v[cc]);
      v[cc] = f2bs(carry);
      carry += f;
    }
#pragma unroll
    for (int cc = 0; cc < 64; ++cc) zmir[base + (size_t)cc * 64] = v[cc];
  }
}

// ---------------------------------------------------------------------------
// K3 (2 chunks/block, reg-held weight frags, transposed-compute):
//   y = (Q Sprev + tril(Q K^T) V) / (q.zprev + rowsum(A) + eps)
// ---------------------------------------------------------------------------
__global__ __launch_bounds__(256) void k_y(
    const float* __restrict__ x, const unsigned short* __restrict__ wqT,
    const unsigned short* __restrict__ wkT, const unsigned short* __restrict__ wvT,
    const unsigned short* __restrict__ mir, const unsigned short* __restrict__ zmir,
    unsigned short* __restrict__ y)
{
  __shared__ __align__(16) unsigned short Xb[64][72];   // x -> mir[o][e]
  __shared__ __align__(16) unsigned short Qb[64][72];   // WqT -> Q[t][e] -> A[t][s]
  __shared__ __align__(16) unsigned short Kb[64][72];   // WkT -> K[s][e] -> y[t][o]
  __shared__ __align__(16) unsigned short Vt[64][72];   // WvT -> V^T[o][t]

  const int tid = threadIdx.x, blk = blockIdx.x;
  const int cp = blk & 31, bh = blk >> 5, h = bh & 15, b = bh >> 4;
  const int l = tid & 63, w = tid >> 6;
  const int wr = w >> 1, wc = w & 1;
  const int l31 = l & 31, g = l >> 5;

  // --- early coalesced mir + z loads for BOTH chunks (static indices) ---
  uint4 mreg0[2], mreg1[2];
  bf16x8 zf0[4], zf1[4];
  {
    const size_t s0 = (size_t)(bh * 64 + cp * 2);
    const unsigned short* mp0 = mir + s0 * 4096;
    const unsigned short* mp1 = mp0 + 4096;
#pragma unroll
    for (int it = 0; it < 2; ++it) {
      mreg0[it] = *(const uint4*)&mp0[tid * 8 + it * 2048];
      mreg1[it] = *(const uint4*)&mp1[tid * 8 + it * 2048];
    }
    const unsigned short* zp0 = zmir + s0 * 64;
#pragma unroll
    for (int j = 0; j < 4; ++j) {
      zf0[j] = *(const bf16x8*)(zp0 + j * 16 + g * 8);
      zf1[j] = *(const bf16x8*)(zp0 + 64 + j * 16 + g * 8);
    }
  }

  // --- coalesced weight loads -> LDS (once), fragments -> registers ---
  const unsigned short* wqp = wqT + h * 4096;
  const unsigned short* wkp = wkT + h * 4096;
  const unsigned short* wvp = wvT + h * 4096;
#pragma unroll
  for (int it = 0; it < 2; ++it) {
    int j = tid * 8 + it * 2048;
    int r = j >> 6, col = j & 63;
    *(uint4*)&Qb[r][col] = *(const uint4*)&wqp[j];
    *(uint4*)&Kb[r][col] = *(const uint4*)&wkp[j];
    *(uint4*)&Vt[r][col] = *(const uint4*)&wvp[j];
  }
  __syncthreads();
  bf16x8 wqf[4], wkf[4], wvf[4];
#pragma unroll
  for (int j = 0; j < 4; ++j) {
    wqf[j] = *(const bf16x8*)&Qb[wc * 32 + l31][j * 16 + g * 8];
    wkf[j] = *(const bf16x8*)&Kb[wc * 32 + l31][j * 16 + g * 8];
    wvf[j] = *(const bf16x8*)&Vt[wc * 32 + l31][j * 16 + g * 8];
  }

#pragma unroll
  for (int cc = 0; cc < 2; ++cc) {
    const int c = cp * 2 + cc;
    if (cc) __syncthreads();   // prev chunk's buffer reads complete

    // coalesced x load + cvt -> Xb
    const float* xbase = x + ((size_t)(b * Sv + c * 64)) * 1024 + h * 64;
#pragma unroll
    for (int it = 0; it < 4; ++it) {
      int u = tid + it * 256;
      int r = u >> 4, seg = u & 15;
      float4 f = *(const float4*)(xbase + (size_t)r * 1024 + seg * 4);
      u16x4 p; p[0] = f2bs(f.x); p[1] = f2bs(f.y); p[2] = f2bs(f.z); p[3] = f2bs(f.w);
      *(u16x4*)&Xb[r][seg * 4] = p;
    }
    __syncthreads();   // bar0: x staged

    bf16x8 xa[4];
#pragma unroll
    for (int j = 0; j < 4; ++j)
      xa[j] = *(const bf16x8*)&Xb[wr * 32 + l31][j * 16 + g * 8];
    // Q^T, K^T ladders (transposed); V ladder (normal) — reg weight frags
    f32x16 qacc = zero16(), kacc = zero16(), vacc = zero16();
#pragma unroll
    for (int j = 0; j < 4; ++j) {
      qacc = MFMA32(wqf[j], xa[j], qacc);
      kacc = MFMA32(wkf[j], xa[j], kacc);
      vacc = MFMA32(xa[j], wvf[j], vacc);
    }
    __syncthreads();   // bar1: x consumed (weights live in registers)

    // stage Q[t][e], K[s][e], V^T[o][t] (packed); mir regs -> Xb[o][e]
#pragma unroll
    for (int q4 = 0; q4 < 4; ++q4) {
      u16x4 pq, pk, pv;
#pragma unroll
      for (int i = 0; i < 4; ++i) {
        pq[i] = f2bs(elu1(qacc[q4 * 4 + i]));
        pk[i] = f2bs(elu1(kacc[q4 * 4 + i]));
        pv[i] = f2bs(vacc[q4 * 4 + i]);
      }
      *(u16x4*)&Qb[wr * 32 + l31][wc * 32 + 8 * q4 + 4 * g] = pq;
      *(u16x4*)&Kb[wr * 32 + l31][wc * 32 + 8 * q4 + 4 * g] = pk;
      *(u16x4*)&Vt[wc * 32 + l31][wr * 32 + 8 * q4 + 4 * g] = pv;
    }
#pragma unroll
    for (int it = 0; it < 2; ++it) {
      int j = tid * 8 + it * 2048;
      int r = j >> 6, col = j & 63;
      *(uint4*)&Xb[r][col] = cc ? mreg1[it] : mreg0[it];
    }
    __syncthreads();   // bar2: Q,K,V^T,mir staged

    bf16x8 qa[4];
#pragma unroll
    for (int j = 0; j < 4; ++j)
      qa[j] = *(const bf16x8*)&Qb[wr * 32 + l31][j * 16 + g * 8];

    // y^T (QS): MFMA(S^T-rows, Q); den: MFMA(z-splat, Q); A^T: MFMA(K, Q)
    f32x16 aacc = zero16(), nacc = zero16(), dacc = zero16();
#pragma unroll
    for (int j = 0; j < 4; ++j) {
      bf16x8 sA = *(const bf16x8*)&Xb[wc * 32 + l31][j * 16 + g * 8];
      nacc = MFMA32(sA, qa[j], nacc);
      dacc = MFMA32(cc ? zf1[j] : zf0[j], qa[j], dacc);
    }
    if (w != 1) {  // wave 1 (t<32, s>=32) strictly upper -> A quadrant = 0
#pragma unroll
      for (int j = 0; j < 4; ++j) {
        bf16x8 kA = *(const bf16x8*)&Kb[wc * 32 + l31][j * 16 + g * 8];
        aacc = MFMA32(kA, qa[j], aacc);
      }
      if (w == 0 || w == 3) {  // diagonal: zero s > t (s=pattern, t=l31)
#pragma unroll
        for (int r = 0; r < 16; ++r)
          if ((r & 3) + 8 * (r >> 2) + 4 * g > l31) aacc[r] = 0.f;
      }
    }
    __syncthreads();   // bar3: Qb(Q) / Kb(K) consumed

    // stage A[t][s] packed
    if (w != 1) {
#pragma unroll
      for (int q4 = 0; q4 < 4; ++q4) {
        u16x4 p;
#pragma unroll
        for (int i = 0; i < 4; ++i) p[i] = f2bs(aacc[q4 * 4 + i]);
        *(u16x4*)&Qb[wr * 32 + l31][wc * 32 + 8 * q4 + 4 * g] = p;
      }
    }
    __syncthreads();   // bar4: A staged

    // y^T += V^T-rows . A ; den += ones . A (row-replicated rowsum)
    const bf16x8 one = ones8();
    const int jmax = (wr == 0) ? 2 : 4;   // t<32 -> only s<32 contributes
#pragma unroll
    for (int j = 0; j < 4; ++j) {
      if (j >= jmax) break;
      bf16x8 aA = *(const bf16x8*)&Qb[wr * 32 + l31][j * 16 + g * 8];
      bf16x8 vA = *(const bf16x8*)&Vt[wc * 32 + l31][j * 16 + g * 8];
      nacc = MFMA32(vA, aA, nacc);
      dacc = MFMA32(one, aA, dacc);
    }

    // ONE rcp per lane (dacc row-replicated)
    const float invd = __builtin_amdgcn_rcpf(dacc[0] + 1e-6f);
    // stage y[t][o] packed — wave-private quadrant
#pragma unroll
    for (int q4 = 0; q4 < 4; ++q4) {
      u16x4 p;
#pragma unroll
      for (int i = 0; i < 4; ++i) p[i] = f2bs(nacc[q4 * 4 + i] * invd);
      *(u16x4*)&Kb[wr * 32 + l31][wc * 32 + 8 * q4 + 4 * g] = p;
    }
    // wave-private coalesced store (in-wave DS order; NO barrier)
    unsigned short* yb = y + ((size_t)(b * Sv + c * 64)) * 1024 + h * 64;
#pragma unroll
    for (int i = 0; i < 2; ++i) {
      int unit = l + i * 64;
      int t_loc = unit >> 2, seg = unit & 3;
      uint4 q = *(const uint4*)&Kb[wr * 32 + t_loc][wc * 32 + seg * 8];
      *(uint4*)&yb[(size_t)(wr * 32 + t_loc) * 1024 + wc * 32 + seg * 8] = q;
    }
  }
}

// ---------------------------------------------------------------------------
// K4 (coalesced-staged 32x32 MFMA): out = y @ Wp. 64 rows/block, 4 waves.
// K=1024 split into 8 x 128-col LDS-staged tiles; dual accumulator chains.
// ---------------------------------------------------------------------------
__global__ __launch_bounds__(256) void k_proj(
    const unsigned short* __restrict__ y, const unsigned short* __restrict__ wpT,
    float* __restrict__ out)
{
  __shared__ __align__(16) unsigned short Ys[64][136];
  __shared__ __align__(16) unsigned short Ws[64][136];

  const int tid = threadIdx.x, bid = blockIdx.x;
  const int l = tid & 63, w = tid >> 6;
  const int wr = w >> 1, wc = w & 1;
  const int l31 = l & 31, g = l >> 5;
  const size_t row0 = (size_t)bid * 64;

  f32x16 acc0 = zero16(), acc1 = zero16();
#pragma unroll 1
  for (int kc = 0; kc < 8; ++kc) {
    __syncthreads();   // prev tiles consumed
#pragma unroll
    for (int it = 0; it < 4; ++it) {
      int u = tid + it * 256;
      int r = u >> 4, seg = u & 15;
      *(uint4*)&Ys[r][seg * 8] =
          *(const uint4*)&y[(row0 + r) * 1024 + kc * 128 + seg * 8];
      *(uint4*)&Ws[r][seg * 8] =
          *(const uint4*)&wpT[(size_t)r * 1024 + kc * 128 + seg * 8];
    }
    __syncthreads();   // tiles staged
#pragma unroll
    for (int jj = 0; jj < 8; jj += 2) {
      bf16x8 a0 = *(const bf16x8*)&Ys[wr * 32 + l31][jj * 16 + g * 8];
      bf16x8 b0 = *(const bf16x8*)&Ws[wc * 32 + l31][jj * 16 + g * 8];
      acc0 = MFMA32(a0, b0, acc0);
      bf16x8 a1 = *(const bf16x8*)&Ys[wr * 32 + l31][(jj + 1) * 16 + g * 8];
      bf16x8 b1 = *(const bf16x8*)&Ws[wc * 32 + l31][(jj + 1) * 16 + g * 8];
      acc1 = MFMA32(a1, b1, acc1);
    }
  }
  float* op = out + (row0 + wr * 32) * 64 + wc * 32;
#pragma unroll
  for (int r = 0; r < 16; ++r)
    op[(size_t)((r & 3) + 8 * (r >> 2) + 4 * g) * 64 + l31] = acc0[r] + acc1[r];
}

// ---------------------------------------------------------------------------
extern "C" void kernel_launch(void* const* d_in, const int* in_sizes, int n_in,
                              void* d_out, int out_size, void* d_ws, size_t ws_size,
                              hipStream_t stream)
{
  const float* x  = (const float*)d_in[0];
  const float* Wq = (const float*)d_in[1];
  const float* Wk = (const float*)d_in[2];
  const float* Wv = (const float*)d_in[3];
  const float* Wp = (const float*)d_in[4];
  float* out = (float*)d_out;

  // ws layout: mir bf16 33.55 MB | zmir bf16 0.52 | wqT/wkT/wvT/wpT 0.52 |
  //            y bf16 [16384][1024] 33.55 MB      (total ~68 MB)
  unsigned short* mir = (unsigned short*)d_ws;
  unsigned short* zmir = mir + 16777216;
  unsigned short* wqT = zmir + 262144;
  unsigned short* wkT = wqT + 65536;
  unsigned short* wvT = wkT + 65536;
  unsigned short* wpT = wvT + 65536;
  unsigned short* yb  = wpT + 65536;

  hipLaunchKernelGGL(k_prep_w, dim3(80), dim3(256), 0, stream,
                     Wq, Wk, Wv, Wp, wqT, wkT, wvT, wpT);
  hipLaunchKernelGGL(k_chunk_state, dim3(BHv * NCv / 2), dim3(256), 0, stream,
                     x, wkT, wvT, mir, zmir);
  hipLaunchKernelGGL(k_prefix, dim3(BHv * 9), dim3(256), 0, stream, mir, zmir);
  hipLaunchKernelGGL(k_y, dim3(BHv * NCv / 2), dim3(256), 0, stream,
                     x, wqT, wkT, wvT, mir, zmir, yb);
  hipLaunchKernelGGL(k_proj, dim3((Bv * Sv) / 64), dim3(256), 0, stream,
                     yb, wpT, out);
}

// Round 19
// 87.438 us; speedup vs baseline: 1.1327x; 1.1327x over previous
//
#include <hip/hip_runtime.h>
#include <hip/hip_bf16.h>

// Problem constants
#define Bv 4
#define Sv 4096
#define Dv 1024
#define Hv 16
#define Ov 64
#define NCv 64
#define BHv 64

typedef __attribute__((ext_vector_type(8))) short bf16x8;
typedef __attribute__((ext_vector_type(4))) unsigned short u16x4;
typedef __attribute__((ext_vector_type(8))) unsigned short u16x8;
typedef __attribute__((ext_vector_type(4))) float f32x4;
typedef __attribute__((ext_vector_type(16))) float f32x16;
#define MFMA32(a, b, c) __builtin_amdgcn_mfma_f32_32x32x16_bf16(a, b, c, 0, 0, 0)

__device__ __forceinline__ unsigned short f2bs(float f) {
  union { __hip_bfloat16 h; unsigned short u; } v;
  v.h = __float2bfloat16(f);
  return v.u;
}
__device__ __forceinline__ float b2f(unsigned short u) {
  union { unsigned u; float f; } v; v.u = ((unsigned)u) << 16; return v.f;
}
__device__ __forceinline__ float elu1(float a) {
  return a > 0.f ? a + 1.f : __expf(a);
}
__device__ __forceinline__ f32x16 zero16() {
  f32x16 v;
#pragma unroll
  for (int i = 0; i < 16; ++i) v[i] = 0.f;
  return v;
}
__device__ __forceinline__ bf16x8 ones8() {
  union { u16x8 u; bf16x8 h; } r;
#pragma unroll
  for (int i = 0; i < 8; ++i) r.u[i] = 0x3F80;   // bf16 1.0
  return r.h;
}

// ---------------------------------------------------------------------------
// K0 prep: Wq/Wk/Wv [h][d][o] -> bf16 [h][o][d]; Wp [d][o2] -> bf16 [o2][d]
// ---------------------------------------------------------------------------
__global__ __launch_bounds__(256) void k_prep_w(
    const float* __restrict__ Wq, const float* __restrict__ Wk,
    const float* __restrict__ Wv, const float* __restrict__ Wp,
    unsigned short* __restrict__ wqT, unsigned short* __restrict__ wkT,
    unsigned short* __restrict__ wvT, unsigned short* __restrict__ wpT)
{
  const int blk = blockIdx.x, tid = threadIdx.x;
  if (blk < 16) {
    int h = blk;
    for (int j = tid; j < 4096; j += 256) {       // j = o*64 + d (output idx)
      int o = j >> 6, d = j & 63;
      int src = h * 4096 + d * 64 + o;
      wqT[h * 4096 + j] = f2bs(Wq[src]);
      wkT[h * 4096 + j] = f2bs(Wk[src]);
      wvT[h * 4096 + j] = f2bs(Wv[src]);
    }
  } else {
    int b2 = blk - 16;
#pragma unroll
    for (int k = 0; k < 4; ++k) {
      int j = b2 * 1024 + tid + k * 256;          // j = o2*1024 + d
      int o = j >> 10, d = j & 1023;
      wpT[j] = f2bs(Wp[d * 64 + o]);
    }
  }
}

// ---------------------------------------------------------------------------
// K1 (coalesced-staged): per (bh,chunk): K=elu1(x Wk), V=x Wv
//   mir [o][e] = (K^T V)^T bf16 ; zmir [e] = colsum(K) bf16
// ---------------------------------------------------------------------------
__global__ __launch_bounds__(256) void k_chunk_state(
    const float* __restrict__ x, const unsigned short* __restrict__ wkT,
    const unsigned short* __restrict__ wvT, unsigned short* __restrict__ mir,
    unsigned short* __restrict__ zmir)
{
  __shared__ __align__(16) unsigned short Xb[64][72];   // x tile -> mir stage
  __shared__ __align__(16) unsigned short Kt[64][72];   // WkT -> K^T[e][t]
  __shared__ __align__(16) unsigned short Vt[64][72];   // WvT -> V^T[o][t]

  const int tid = threadIdx.x, blk = blockIdx.x;
  const int c = blk & 63, bh = blk >> 6, h = bh & 15, b = bh >> 4;
  const int l = tid & 63, w = tid >> 6;
  const int wr = w >> 1, wc = w & 1;
  const int l31 = l & 31, g = l >> 5;

  // --- coalesced weight loads -> LDS ---
  const unsigned short* wkp = wkT + h * 4096;
  const unsigned short* wvp = wvT + h * 4096;
#pragma unroll
  for (int it = 0; it < 2; ++it) {
    int j = tid * 8 + it * 2048;
    int r = j >> 6, col = j & 63;
    *(uint4*)&Kt[r][col] = *(const uint4*)&wkp[j];
    *(uint4*)&Vt[r][col] = *(const uint4*)&wvp[j];
  }
  // --- coalesced x load (f32, per-row 256B segments) + cvt -> Xb ---
  const float* xbase = x + ((size_t)(b * Sv + c * 64)) * 1024 + h * 64;
#pragma unroll
  for (int it = 0; it < 4; ++it) {
    int u = tid + it * 256;
    int r = u >> 4, seg = u & 15;
    float4 f = *(const float4*)(xbase + (size_t)r * 1024 + seg * 4);
    u16x4 p; p[0] = f2bs(f.x); p[1] = f2bs(f.y); p[2] = f2bs(f.z); p[3] = f2bs(f.w);
    *(u16x4*)&Xb[r][seg * 4] = p;
  }
  __syncthreads();   // bar0: staging done

  // fragments from LDS
  bf16x8 xa[4], wkf[4], wvf[4];
#pragma unroll
  for (int j = 0; j < 4; ++j) {
    xa[j]  = *(const bf16x8*)&Xb[wr * 32 + l31][j * 16 + g * 8];
    wkf[j] = *(const bf16x8*)&Kt[wc * 32 + l31][j * 16 + g * 8];
    wvf[j] = *(const bf16x8*)&Vt[wc * 32 + l31][j * 16 + g * 8];
  }
  // K, V ladders (normal orientation: D[t][e])
  f32x16 kacc = zero16(), vacc = zero16();
#pragma unroll
  for (int j = 0; j < 4; ++j) {
    kacc = MFMA32(xa[j], wkf[j], kacc);
    vacc = MFMA32(xa[j], wvf[j], vacc);
  }
  __syncthreads();   // bar1: weights consumed

  // stage K^T[e][t] / V^T[o][t], packed along t
#pragma unroll
  for (int q4 = 0; q4 < 4; ++q4) {
    u16x4 pk, pv;
#pragma unroll
    for (int i = 0; i < 4; ++i) {
      pk[i] = f2bs(elu1(kacc[q4 * 4 + i]));
      pv[i] = f2bs(vacc[q4 * 4 + i]);
    }
    *(u16x4*)&Kt[wc * 32 + l31][wr * 32 + 8 * q4 + 4 * g] = pk;
    *(u16x4*)&Vt[wc * 32 + l31][wr * 32 + 8 * q4 + 4 * g] = pv;
  }
  __syncthreads();   // bar2: K^T, V^T staged

  // KtV: D[e][o]; z = ones . K^T-cols (col-replicated)
  f32x16 sacc = zero16(), zacc = zero16();
  const bf16x8 one = ones8();
#pragma unroll
  for (int j = 0; j < 4; ++j) {
    bf16x8 aK = *(const bf16x8*)&Kt[wr * 32 + l31][j * 16 + g * 8];
    bf16x8 vB = *(const bf16x8*)&Vt[wc * 32 + l31][j * 16 + g * 8];
    sacc = MFMA32(aK, vB, sacc);
    bf16x8 kB = *(const bf16x8*)&Kt[wc * 32 + l31][j * 16 + g * 8];
    zacc = MFMA32(one, kB, zacc);
  }
  // stage mir[o][e] into Xb (packed along e): row o = wc*32+l31, cols e
#pragma unroll
  for (int q4 = 0; q4 < 4; ++q4) {
    u16x4 p;
#pragma unroll
    for (int i = 0; i < 4; ++i) p[i] = f2bs(sacc[q4 * 4 + i]);
    *(u16x4*)&Xb[wc * 32 + l31][wr * 32 + 8 * q4 + 4 * g] = p;
  }
  __syncthreads();   // bar3: mir staged

  // coalesced mir store
  unsigned short* mp = mir + (size_t)blk * 4096;
#pragma unroll
  for (int it = 0; it < 2; ++it) {
    int j = tid * 8 + it * 2048;
    int r = j >> 6, col = j & 63;
    *(uint4*)&mp[j] = *(const uint4*)&Xb[r][col];
  }
  if (w < 2 && g == 0)
    zmir[(size_t)blk * 64 + wc * 32 + l31] = f2bs(zacc[0]);
}

// ---------------------------------------------------------------------------
// K2: exclusive prefix over chunks — u32-vectorized (2 bf16/thread).
// grid = 64 bh * 9 groups (8 mir + 1 z).
// ---------------------------------------------------------------------------
__global__ __launch_bounds__(256) void k_prefix(
    unsigned short* __restrict__ mir, unsigned short* __restrict__ zmir)
{
  const int bh = blockIdx.x / 9, g = blockIdx.x % 9;
  const int tid = threadIdx.x;
  if (g < 8) {
    size_t base = (size_t)bh * 64 * 4096 + g * 512 + tid * 2;
    const unsigned short* mp = mir + base;
    unsigned v[64];
#pragma unroll
    for (int cc = 0; cc < 64; ++cc)
      v[cc] = *(const unsigned*)(mp + (size_t)cc * 4096);
    float c0 = 0.f, c1 = 0.f;
#pragma unroll
    for (int cc = 0; cc < 64; ++cc) {
      float f0 = b2f((unsigned short)(v[cc] & 0xffffu));
      float f1 = b2f((unsigned short)(v[cc] >> 16));
      v[cc] = (unsigned)f2bs(c0) | ((unsigned)f2bs(c1) << 16);
      c0 += f0; c1 += f1;
    }
    unsigned short* mw = mir + base;
#pragma unroll
    for (int cc = 0; cc < 64; ++cc)
      *(unsigned*)(mw + (size_t)cc * 4096) = v[cc];
  } else if (tid < 64) {
    size_t base = (size_t)bh * 64 * 64 + tid;
    unsigned short v[64];
#pragma unroll
    for (int cc = 0; cc < 64; ++cc) v[cc] = zmir[base + (size_t)cc * 64];
    float carry = 0.f;
#pragma unroll
    for (int cc = 0; cc < 64; ++cc) {
      float f = b2f(v[cc]);
      v[cc] = f2bs(carry);
      carry += f;
    }
#pragma unroll
    for (int cc = 0; cc < 64; ++cc) zmir[base + (size_t)cc * 64] = v[cc];
  }
}

// ---------------------------------------------------------------------------
// K3 (coalesced-staged, transposed-compute): per (b,h,chunk):
//   y = (Q Sprev + tril(Q K^T) V) / (q.zprev + rowsum(A) + eps)
// ---------------------------------------------------------------------------
__global__ __launch_bounds__(256) void k_y(
    const float* __restrict__ x, const unsigned short* __restrict__ wqT,
    const unsigned short* __restrict__ wkT, const unsigned short* __restrict__ wvT,
    const unsigned short* __restrict__ mir, const unsigned short* __restrict__ zmir,
    unsigned short* __restrict__ y)
{
  __shared__ __align__(16) unsigned short Xb[64][72];   // x -> mir[o][e]
  __shared__ __align__(16) unsigned short Qb[64][72];   // WqT -> Q[t][e] -> A[t][s]
  __shared__ __align__(16) unsigned short Kb[64][72];   // WkT -> K[s][e] -> y[t][o]
  __shared__ __align__(16) unsigned short Vt[64][72];   // WvT -> V^T[o][t]

  const int tid = threadIdx.x, blk = blockIdx.x;
  const int c = blk & 63, bh = blk >> 6, h = bh & 15, b = bh >> 4;
  const int l = tid & 63, w = tid >> 6;
  const int wr = w >> 1, wc = w & 1;
  const int l31 = l & 31, g = l >> 5;
  const size_t sblk = (size_t)blk;

  // --- early coalesced mir load -> regs (hides under staging) ---
  const unsigned short* mp = mir + sblk * 4096;
  uint4 mreg[2];
#pragma unroll
  for (int it = 0; it < 2; ++it)
    mreg[it] = *(const uint4*)&mp[tid * 8 + it * 2048];
  // z splat fragments (lane-group-uniform 16B loads)
  const unsigned short* zp = zmir + sblk * 64;
  bf16x8 zf[4];
#pragma unroll
  for (int j = 0; j < 4; ++j)
    zf[j] = *(const bf16x8*)(zp + j * 16 + g * 8);

  // --- coalesced weight loads -> LDS ---
  const unsigned short* wqp = wqT + h * 4096;
  const unsigned short* wkp = wkT + h * 4096;
  const unsigned short* wvp = wvT + h * 4096;
#pragma unroll
  for (int it = 0; it < 2; ++it) {
    int j = tid * 8 + it * 2048;
    int r = j >> 6, col = j & 63;
    *(uint4*)&Qb[r][col] = *(const uint4*)&wqp[j];
    *(uint4*)&Kb[r][col] = *(const uint4*)&wkp[j];
    *(uint4*)&Vt[r][col] = *(const uint4*)&wvp[j];
  }
  // --- coalesced x load + cvt -> Xb ---
  const float* xbase = x + ((size_t)(b * Sv + c * 64)) * 1024 + h * 64;
#pragma unroll
  for (int it = 0; it < 4; ++it) {
    int u = tid + it * 256;
    int r = u >> 4, seg = u & 15;
    float4 f = *(const float4*)(xbase + (size_t)r * 1024 + seg * 4);
    u16x4 p; p[0] = f2bs(f.x); p[1] = f2bs(f.y); p[2] = f2bs(f.z); p[3] = f2bs(f.w);
    *(u16x4*)&Xb[r][seg * 4] = p;
  }
  __syncthreads();   // bar0: staging done

  // fragments from LDS
  bf16x8 xa[4], wqf[4], wkf[4], wvf[4];
#pragma unroll
  for (int j = 0; j < 4; ++j) {
    xa[j]  = *(const bf16x8*)&Xb[wr * 32 + l31][j * 16 + g * 8];
    wqf[j] = *(const bf16x8*)&Qb[wc * 32 + l31][j * 16 + g * 8];
    wkf[j] = *(const bf16x8*)&Kb[wc * 32 + l31][j * 16 + g * 8];
    wvf[j] = *(const bf16x8*)&Vt[wc * 32 + l31][j * 16 + g * 8];
  }
  // Q^T, K^T ladders (transposed: D[e][t] / D[e][s]); V ladder (normal D[t][o])
  f32x16 qacc = zero16(), kacc = zero16(), vacc = zero16();
#pragma unroll
  for (int j = 0; j < 4; ++j) {
    qacc = MFMA32(wqf[j], xa[j], qacc);
    kacc = MFMA32(wkf[j], xa[j], kacc);
    vacc = MFMA32(xa[j], wvf[j], vacc);
  }
  __syncthreads();   // bar1: weights + x consumed

  // stage Q[t][e], K[s][e], V^T[o][t] (all packed); mir regs -> Xb[o][e]
#pragma unroll
  for (int q4 = 0; q4 < 4; ++q4) {
    u16x4 pq, pk, pv;
#pragma unroll
    for (int i = 0; i < 4; ++i) {
      pq[i] = f2bs(elu1(qacc[q4 * 4 + i]));
      pk[i] = f2bs(elu1(kacc[q4 * 4 + i]));
      pv[i] = f2bs(vacc[q4 * 4 + i]);
    }
    *(u16x4*)&Qb[wr * 32 + l31][wc * 32 + 8 * q4 + 4 * g] = pq;
    *(u16x4*)&Kb[wr * 32 + l31][wc * 32 + 8 * q4 + 4 * g] = pk;
    *(u16x4*)&Vt[wc * 32 + l31][wr * 32 + 8 * q4 + 4 * g] = pv;
  }
#pragma unroll
  for (int it = 0; it < 2; ++it) {
    int j = tid * 8 + it * 2048;
    int r = j >> 6, col = j & 63;
    *(uint4*)&Xb[r][col] = mreg[it];
  }
  __syncthreads();   // bar2: Q,K,V^T,mir staged

  // qa fragments (rows t = wr*32 + l31, full e)
  bf16x8 qa[4];
#pragma unroll
  for (int j = 0; j < 4; ++j)
    qa[j] = *(const bf16x8*)&Qb[wr * 32 + l31][j * 16 + g * 8];

  // y^T (QS): D[o][t] = MFMA(S^T-rows, Q); den: MFMA(z-splat, Q); A^T: MFMA(K, Q)
  f32x16 aacc = zero16(), nacc = zero16(), dacc = zero16();
#pragma unroll
  for (int j = 0; j < 4; ++j) {
    bf16x8 sA = *(const bf16x8*)&Xb[wc * 32 + l31][j * 16 + g * 8];
    nacc = MFMA32(sA, qa[j], nacc);
    dacc = MFMA32(zf[j], qa[j], dacc);
  }
  if (w != 1) {  // wave 1 (t<32, s>=32) strictly upper -> A quadrant = 0
#pragma unroll
    for (int j = 0; j < 4; ++j) {
      bf16x8 kA = *(const bf16x8*)&Kb[wc * 32 + l31][j * 16 + g * 8];
      aacc = MFMA32(kA, qa[j], aacc);
    }
    if (w == 0 || w == 3) {  // diagonal: zero s > t (s=pattern, t=l31)
#pragma unroll
      for (int r = 0; r < 16; ++r)
        if ((r & 3) + 8 * (r >> 2) + 4 * g > l31) aacc[r] = 0.f;
    }
  }
  __syncthreads();   // bar3: Qb(Q) / Kb(K) consumed

  // stage A[t][s] packed
  if (w != 1) {
#pragma unroll
    for (int q4 = 0; q4 < 4; ++q4) {
      u16x4 p;
#pragma unroll
      for (int i = 0; i < 4; ++i) p[i] = f2bs(aacc[q4 * 4 + i]);
      *(u16x4*)&Qb[wr * 32 + l31][wc * 32 + 8 * q4 + 4 * g] = p;
    }
  }
  __syncthreads();   // bar4: A staged

  // y^T += V^T-rows . A ; den += ones . A (row-replicated rowsum)
  const bf16x8 one = ones8();
  const int jmax = (wr == 0) ? 2 : 4;   // t<32 -> only s<32 contributes
#pragma unroll
  for (int j = 0; j < 4; ++j) {
    if (j >= jmax) break;
    bf16x8 aA = *(const bf16x8*)&Qb[wr * 32 + l31][j * 16 + g * 8];
    bf16x8 vA = *(const bf16x8*)&Vt[wc * 32 + l31][j * 16 + g * 8];
    nacc = MFMA32(vA, aA, nacc);
    dacc = MFMA32(one, aA, dacc);
  }

  // ONE rcp per lane (dacc row-replicated; den of row t = wr*32+l31)
  const float invd = __builtin_amdgcn_rcpf(dacc[0] + 1e-6f);
  // stage y[t][o] packed — wave-private quadrant
#pragma unroll
  for (int q4 = 0; q4 < 4; ++q4) {
    u16x4 p;
#pragma unroll
    for (int i = 0; i < 4; ++i) p[i] = f2bs(nacc[q4 * 4 + i] * invd);
    *(u16x4*)&Kb[wr * 32 + l31][wc * 32 + 8 * q4 + 4 * g] = p;
  }
  // wave-private coalesced store (in-wave DS order; NO barrier)
  unsigned short* yb = y + ((size_t)(b * Sv + c * 64)) * 1024 + h * 64;
#pragma unroll
  for (int i = 0; i < 2; ++i) {
    int unit = l + i * 64;
    int t_loc = unit >> 2, seg = unit & 3;
    uint4 q = *(const uint4*)&Kb[wr * 32 + t_loc][wc * 32 + seg * 8];
    *(uint4*)&yb[(size_t)(wr * 32 + t_loc) * 1024 + wc * 32 + seg * 8] = q;
  }
}

// ---------------------------------------------------------------------------
// K4 (coalesced-staged 32x32 MFMA): out = y @ Wp. 64 rows/block, 4 waves.
// K=1024 split into 8 x 128-col LDS-staged tiles; dual accumulator chains.
// ---------------------------------------------------------------------------
__global__ __launch_bounds__(256) void k_proj(
    const unsigned short* __restrict__ y, const unsigned short* __restrict__ wpT,
    float* __restrict__ out)
{
  __shared__ __align__(16) unsigned short Ys[64][136];
  __shared__ __align__(16) unsigned short Ws[64][136];

  const int tid = threadIdx.x, bid = blockIdx.x;
  const int l = tid & 63, w = tid >> 6;
  const int wr = w >> 1, wc = w & 1;
  const int l31 = l & 31, g = l >> 5;
  const size_t row0 = (size_t)bid * 64;

  f32x16 acc0 = zero16(), acc1 = zero16();
#pragma unroll 1
  for (int kc = 0; kc < 8; ++kc) {
    __syncthreads();   // prev tiles consumed
#pragma unroll
    for (int it = 0; it < 4; ++it) {
      int u = tid + it * 256;
      int r = u >> 4, seg = u & 15;
      *(uint4*)&Ys[r][seg * 8] =
          *(const uint4*)&y[(row0 + r) * 1024 + kc * 128 + seg * 8];
      *(uint4*)&Ws[r][seg * 8] =
          *(const uint4*)&wpT[(size_t)r * 1024 + kc * 128 + seg * 8];
    }
    __syncthreads();   // tiles staged
#pragma unroll
    for (int jj = 0; jj < 8; jj += 2) {
      bf16x8 a0 = *(const bf16x8*)&Ys[wr * 32 + l31][jj * 16 + g * 8];
      bf16x8 b0 = *(const bf16x8*)&Ws[wc * 32 + l31][jj * 16 + g * 8];
      acc0 = MFMA32(a0, b0, acc0);
      bf16x8 a1 = *(const bf16x8*)&Ys[wr * 32 + l31][(jj + 1) * 16 + g * 8];
      bf16x8 b1 = *(const bf16x8*)&Ws[wc * 32 + l31][(jj + 1) * 16 + g * 8];
      acc1 = MFMA32(a1, b1, acc1);
    }
  }
  float* op = out + (row0 + wr * 32) * 64 + wc * 32;
#pragma unroll
  for (int r = 0; r < 16; ++r)
    op[(size_t)((r & 3) + 8 * (r >> 2) + 4 * g) * 64 + l31] = acc0[r] + acc1[r];
}

// ---------------------------------------------------------------------------
extern "C" void kernel_launch(void* const* d_in, const int* in_sizes, int n_in,
                              void* d_out, int out_size, void* d_ws, size_t ws_size,
                              hipStream_t stream)
{
  const float* x  = (const float*)d_in[0];
  const float* Wq = (const float*)d_in[1];
  const float* Wk = (const float*)d_in[2];
  const float* Wv = (const float*)d_in[3];
  const float* Wp = (const float*)d_in[4];
  float* out = (float*)d_out;

  // ws layout: mir bf16 33.55 MB | zmir bf16 0.52 | wqT/wkT/wvT/wpT 0.52 |
  //            y bf16 [16384][1024] 33.55 MB      (total ~68 MB)
  unsigned short* mir = (unsigned short*)d_ws;
  unsigned short* zmir = mir + 16777216;
  unsigned short* wqT = zmir + 262144;
  unsigned short* wkT = wqT + 65536;
  unsigned short* wvT = wkT + 65536;
  unsigned short* wpT = wvT + 65536;
  unsigned short* yb  = wpT + 65536;

  hipLaunchKernelGGL(k_prep_w, dim3(80), dim3(256), 0, stream,
                     Wq, Wk, Wv, Wp, wqT, wkT, wvT, wpT);
  hipLaunchKernelGGL(k_chunk_state, dim3(BHv * NCv), dim3(256), 0, stream,
                     x, wkT, wvT, mir, zmir);
  hipLaunchKernelGGL(k_prefix, dim3(BHv * 9), dim3(256), 0, stream, mir, zmir);
  hipLaunchKernelGGL(k_y, dim3(BHv * NCv), dim3(256), 0, stream,
                     x, wqT, wkT, wvT, mir, zmir, yb);
  hipLaunchKernelGGL(k_proj, dim3((Bv * Sv) / 64), dim3(256), 0, stream,
                     yb, wpT, out);
}